// Round 3
// baseline (265.607 us; speedup 1.0000x reference)
//
#include <hip/hip_runtime.h>
#include <hip/hip_fp16.h>

#define NBC 14
#define NAC 45
#define KF  52
#define RHO 0.05f
#define TT  4096
#define BB  64
#define CH  128          // output steps per chunk
#define WU  160          // warmup steps
#define NCHUNK 32        // TT / CH
#define NTMAX (CH + WU)  // 288
#define XPAD  (NTMAX + 8)   // xf_lds row stride in halfs
#define XLN   (NTMAX + KF)  // x slice length incl. halo

__device__ __forceinline__ float readlane_f(float v, int lane) {
  return __int_as_float(__builtin_amdgcn_readlane(__float_as_int(v), lane));
}

__global__ __launch_bounds__(64)
void bcn_kernel(const float* __restrict__ x,
                const float* __restrict__ bck,
                const float* __restrict__ lss,
                const float* __restrict__ soff,
                const float* __restrict__ lbaw,
                const float* __restrict__ ltr,
                const float* __restrict__ ltd,
                const float* __restrict__ lass,
                const float* __restrict__ asoff,
                const float* __restrict__ labw,
                const float* __restrict__ oscale,
                float* __restrict__ out)
{
  __shared__ __half xf_lds[NBC * XPAD];            // conv output (fp16)
  __shared__ float  x_lds[XLN];                    // stimulus slice
  __shared__ __half u_hist[64 * 46];               // ring of u[a] (52-delay)
  __shared__ float ac_st[8 * NAC];                 // output staging (8 steps)
  __shared__ float yb_st[8 * NBC];
  __shared__ float fb_st[8 * NBC];
  __shared__ float yl_st[8 * NBC];

  const int lid   = threadIdx.x;
  const int blk   = blockIdx.x;
  const int b     = blk >> 5;          // batch (NCHUNK=32)
  const int chunk = blk & 31;
  const int t0      = chunk * CH;
  const int warm    = (chunk == 0) ? 0 : WU;
  const int t_begin = t0 - warm;
  const int NT      = CH + warm;       // 128 (chunk 0) or 288

  // ---- zero-init LDS ----
  for (int i = lid; i < (64 * 46) / 2; i += 64) ((unsigned int*)u_hist)[i] = 0u;

  // ---- load stimulus slice (with causal zero pad at t<0) ----
  for (int p = lid; p < NT + KF - 1; p += 64) {
    int gt = t_begin - (KF - 1) + p;
    x_lds[p] = (gt >= 0) ? x[b * TT + gt] : 0.f;
  }
  __syncthreads();

  // ---- causal conv into xf_lds (fp16) ----
  for (int ib = 0; ib < ((NT + 63) >> 6); ++ib) {
    int tau = lid + (ib << 6);
    if (tau < NT) {
      float acc[NBC];
#pragma unroll
      for (int c = 0; c < NBC; ++c) acc[c] = 0.f;
#pragma unroll 4
      for (int k = 0; k < KF; ++k) {
        float xv = x_lds[tau + k];
#pragma unroll
        for (int c = 0; c < NBC; ++c) acc[c] = fmaf(bck[c * KF + k], xv, acc[c]);
      }
#pragma unroll
      for (int c = 0; c < NBC; ++c) xf_lds[c * XPAD + tau] = __float2half(acc[c]);
    }
  }

  // ---- per-lane parameters ----
  float slope_c = 0.f, off_c = 0.f, osc_c = 0.f;
  float pool_b = 1.f, pool_l = 1.f;
  float r1i = 0.f, r2i = 0.f, co1 = 0.f, co2 = 0.f, cn1 = 0.f, cn2 = 0.f;
  float inorm = 0.f, aslope = 0.f, aoff = 0.f;
  float w1r[NBC];     // AC lane a: weights w1[a][c] (rel -> u)
  float w2f[NAC];     // BC lane c: weights -exp(labw[c][a]) (ac -> fb)
  float S1 = 0.f, S2 = 0.f;

#pragma unroll
  for (int i = 0; i < NBC; ++i) w1r[i] = 0.f;
#pragma unroll
  for (int i = 0; i < NAC; ++i) w2f[i] = 0.f;

  if (lid < NBC) {
    slope_c = expf(lss[lid]);
    off_c   = soff[lid];
    osc_c   = oscale[lid];
#pragma unroll
    for (int a = 0; a < NAC; ++a) w2f[a] = -expf(labw[lid * NAC + a]);
  }
  if (lid < NAC) {
    float tr = expf(ltr[lid]);
    float td = expf(ltd[lid]);
    float a1 = 1.f / td;                 // rate of exp(-kt/td)
    float gg = (td + tr) / (td * tr);    // rate of second exponential
    r1i = expf(-a1 * 0.015625f);         // per-step decay
    r2i = expf(-gg * 0.015625f);
    cn1 = expf(-a1 * 0.003125f);         // newest tap weight (kt[51])
    cn2 = expf(-gg * 0.003125f);
    co1 = expf(-a1 * 0.815625f);         // tap falling off (kt[0]+1/64)
    co2 = expf(-gg * 0.815625f);
    float nrm = 0.f;
    for (int k = 0; k < KF; ++k) {
      float kt = 0.8f - (float)k * 0.015625f;
      float d = expf(-a1 * kt) - expf(-gg * kt);
      nrm = fmaf(d, d, nrm);
    }
    inorm  = 1.f / sqrtf(nrm);
    aslope = expf(lass[lid]);
    aoff   = asoff[lid];
#pragma unroll
    for (int j = 0; j < NBC; ++j) w1r[j] = expf(lbaw[lid * NBC + j]);
  }

  // ---- output pointers (flat concat: y_bcn, fb, ac_out, y_lnr) ----
  float* yb  = out;
  float* fbp = out + (size_t)BB * TT * NBC;
  float* acp = out + 2 * (size_t)BB * TT * NBC;
  float* ylp = out + 2 * (size_t)BB * TT * NBC + (size_t)BB * TT * NAC;

  __syncthreads();

  // ---- sequential recurrence (single wave, all cross-lane via readlane) ----
  for (int s = 0; s < NT; ++s) {
    // prefetch (off critical path)
    float uold = 0.f, xfv = 0.f;
    if (lid < NAC) uold = __half2float(u_hist[((s + 12) & 63) * 46 + lid]);
    if (lid < NBC) xfv  = __half2float(xf_lds[lid * XPAD + s]);

    // AC phase: drive -> sigmoid
    float ac = 0.f;
    if (lid < NAC) {
      float drive = (S1 - S2) * inorm;
      float z  = aslope * (drive - aoff);
      ac = __fdividef(1.f, 1.f + __expf(-z));
      ac_st[(s & 7) * NAC + lid] = ac;
    }

    // fb[c] = sum_a w2[c][a] * ac[a] : readlane broadcast + FMA tree
    float fa[6] = {0.f, 0.f, 0.f, 0.f, 0.f, 0.f};
#pragma unroll
    for (int a = 0; a < NAC; ++a)
      fa[a % 6] = fmaf(w2f[a], readlane_f(ac, a), fa[a % 6]);
    float fbv = ((fa[0] + fa[1]) + (fa[2] + fa[3])) + (fa[4] + fa[5]);

    // BC phase: BCN release + (free) LNR branch; stage outputs
    float rel = 0.f;
    if (lid < NBC) {
      float pz   = slope_c * ((xfv + fbv) - off_c);
      float prob = __fdividef(1.f, 1.f + __expf(-pz));
      float pool2 = fmaf(1.f - RHO, pool_b, RHO);
      rel  = prob * pool2;
      pool_b = pool2 - rel;

      float lz = slope_c * (xfv - off_c);
      float pl = __fdividef(1.f, 1.f + __expf(-lz));
      float pool2l = fmaf(1.f - RHO, pool_l, RHO);
      float rll = pl * pool2l;
      pool_l = pool2l - rll;

      int st = (s & 7) * NBC + lid;
      yb_st[st] = osc_c * rel;
      fb_st[st] = fbv;
      yl_st[st] = osc_c * rll;
    }

    // u phase: u[a] = sum_c w1[a][c] * rel[c] via readlane; state update
    if (lid < NAC) {
      float ua[4] = {0.f, 0.f, 0.f, 0.f};
#pragma unroll
      for (int c = 0; c < NBC; ++c)
        ua[c % 4] = fmaf(w1r[c], readlane_f(rel, c), ua[c % 4]);
      float u = (ua[0] + ua[1]) + (ua[2] + ua[3]);

      u_hist[(s & 63) * 46 + lid] = __float2half(u);
      S1 = fmaf(S1, r1i, fmaf(cn1, u, -co1 * uold));
      S2 = fmaf(S2, r2i, fmaf(cn2, u, -co2 * uold));
    }

    // flush staged outputs every 8 steps (coalesced, off critical path)
    if ((s & 7) == 7 && (s - 7) >= warm) {
      asm volatile("" ::: "memory");
      int tg = t_begin + s - 7;
      size_t ob14 = ((size_t)b * TT + tg) * NBC;
      size_t oa45 = ((size_t)b * TT + tg) * NAC;
#pragma unroll
      for (int i = 0; i < 2; ++i) {
        int idx = lid + (i << 6);
        if (idx < 8 * NBC) {
          yb[ob14 + idx]  = yb_st[idx];
          fbp[ob14 + idx] = fb_st[idx];
          ylp[ob14 + idx] = yl_st[idx];
        }
      }
#pragma unroll
      for (int i = 0; i < 6; ++i) {
        int idx = lid + (i << 6);
        if (idx < 8 * NAC) acp[oa45 + idx] = ac_st[idx];
      }
      asm volatile("" ::: "memory");
    }
  }
}

extern "C" void kernel_launch(void* const* d_in, const int* in_sizes, int n_in,
                              void* d_out, int out_size, void* d_ws, size_t ws_size,
                              hipStream_t stream) {
  (void)in_sizes; (void)n_in; (void)d_ws; (void)ws_size; (void)out_size;
  bcn_kernel<<<dim3(BB * NCHUNK), dim3(64), 0, stream>>>(
      (const float*)d_in[0],  // x
      (const float*)d_in[1],  // bc_kernels
      (const float*)d_in[2],  // log_sigmoid_slope
      (const float*)d_in[3],  // sigmoid_offset
      (const float*)d_in[4],  // log_bc_ac_weight
      (const float*)d_in[5],  // log_ac_tau_rise
      (const float*)d_in[6],  // log_ac_tau_decay
      (const float*)d_in[7],  // log_ac_sigmoid_slope
      (const float*)d_in[8],  // ac_sigmoid_offset
      (const float*)d_in[9],  // log_ac_bc_weight
      (const float*)d_in[10], // out_scale
      (float*)d_out);
}

// Round 4
// 203.264 us; speedup vs baseline: 1.3067x; 1.3067x over previous
//
#include <hip/hip_runtime.h>
#include <hip/hip_fp16.h>

#define NBC 14
#define NAC 45
#define KF  52
#define RHO 0.05f
#define TT  4096
#define BB  64
#define CH  128          // output steps per chunk
#define WU  112          // warmup steps (pool err ~0.95^112*0.7 ~ 2e-3 in pool, ~<1e-3 in y)
#define NCHUNK 32        // TT / CH
#define NTMAX (CH + WU)  // 240
#define XPAD  (NTMAX + 8)   // 248, xf_lds row stride in halfs
#define XLN   (NTMAX + KF)  // 292, x slice length incl. halo

// xor-gather within 32-lane halves (bit-mode swizzle; xor<=31 keeps quadrant for J<16)
template<int J>
__device__ __forceinline__ float swzf(float v) {
  return __int_as_float(__builtin_amdgcn_ds_swizzle(__float_as_int(v), (J << 10) | 0x1f));
}

__global__ __launch_bounds__(64)
void bcn_kernel(const float* __restrict__ x,
                const float* __restrict__ bck,
                const float* __restrict__ lss,
                const float* __restrict__ soff,
                const float* __restrict__ lbaw,
                const float* __restrict__ ltr,
                const float* __restrict__ ltd,
                const float* __restrict__ lass,
                const float* __restrict__ asoff,
                const float* __restrict__ labw,
                const float* __restrict__ oscale,
                float* __restrict__ out)
{
  __shared__ __half xf_lds[NBC * XPAD];            // conv output (fp16)
  __shared__ float  x_lds[XLN];                    // stimulus slice
  __shared__ __half u_hist[64 * 46];               // ring of u[a] (52-delay)
  __shared__ float ac_st[8 * NAC];                 // output staging (8 steps)
  __shared__ float yb_st[8 * NBC];
  __shared__ float fb_st[8 * NBC];
  __shared__ float yl_st[8 * NBC];

  const int lid   = threadIdx.x;
  const int c16   = lid & 15;          // BC slot within quadrant
  const int q     = lid >> 4;          // quadrant
  const int blk   = blockIdx.x;
  const int b     = blk >> 5;          // batch (NCHUNK=32)
  const int chunk = blk & 31;
  const int t0      = chunk * CH;
  const int warm    = (chunk == 0) ? 0 : WU;
  const int t_begin = t0 - warm;
  const int NT      = CH + warm;       // 128 (chunk 0) or 240

  // ---- zero-init LDS ----
  for (int i = lid; i < (64 * 46) / 2; i += 64) ((unsigned int*)u_hist)[i] = 0u;

  // ---- load stimulus slice (with causal zero pad at t<0) ----
  for (int p = lid; p < NT + KF - 1; p += 64) {
    int gt = t_begin - (KF - 1) + p;
    x_lds[p] = (gt >= 0) ? x[b * TT + gt] : 0.f;
  }
  __syncthreads();

  // ---- causal conv into xf_lds (fp16) ----
  for (int ib = 0; ib < ((NT + 63) >> 6); ++ib) {
    int tau = lid + (ib << 6);
    if (tau < NT) {
      float acc[NBC];
#pragma unroll
      for (int c = 0; c < NBC; ++c) acc[c] = 0.f;
#pragma unroll 4
      for (int k = 0; k < KF; ++k) {
        float xv = x_lds[tau + k];
#pragma unroll
        for (int c = 0; c < NBC; ++c) acc[c] = fmaf(bck[c * KF + k], xv, acc[c]);
      }
#pragma unroll
      for (int c = 0; c < NBC; ++c) xf_lds[c * XPAD + tau] = __float2half(acc[c]);
    }
  }

  // ---- per-lane parameters ----
  float slope_c = 0.f, soff_s = 0.f, osc_c = 0.f;   // BC (replicated per quadrant)
  float pool_b = 1.f, pool_l = 1.f;
  float r1i = 0.f, r2i = 0.f, co1 = 0.f, co2 = 0.f, cn1 = 0.f, cn2 = 0.f;
  float Adrv = 0.f, Boff = 0.f;                     // AC sigmoid: z = Adrv*(S1-S2) - Boff
  float wfb[16];   // fb gather weights: j -> w2[c16][16q + (c16^j)]
  float wu[16];    // u  gather weights: j -> w1[lid][c16^j]
  float S1 = 0.f, S2 = 0.f;

#pragma unroll
  for (int j = 0; j < 16; ++j) { wfb[j] = 0.f; wu[j] = 0.f; }

  if (c16 < NBC) {
    slope_c = expf(lss[c16]);
    soff_s  = soff[c16] * slope_c;     // pz = slope*xf+slope*fb - soff_s
    osc_c   = oscale[c16];
#pragma unroll
    for (int j = 0; j < 16; ++j) {
      int a = 16 * q + (c16 ^ j);
      if (a < NAC) wfb[j] = -expf(labw[c16 * NAC + a]);
    }
  }
  if (lid < NAC) {
    float tr = expf(ltr[lid]);
    float td = expf(ltd[lid]);
    float a1 = 1.f / td;                 // rate of exp(-kt/td)
    float gg = (td + tr) / (td * tr);    // rate of second exponential
    r1i = expf(-a1 * 0.015625f);         // per-step decay
    r2i = expf(-gg * 0.015625f);
    cn1 = expf(-a1 * 0.003125f);         // newest-tap weight (kt[51])
    cn2 = expf(-gg * 0.003125f);
    co1 = expf(-a1 * 0.815625f);         // tap falling off (kt[0] + 1/64)
    co2 = expf(-gg * 0.815625f);
    float nrm = 0.f;
    for (int k = 0; k < KF; ++k) {
      float kt = 0.8f - (float)k * 0.015625f;
      float d = expf(-a1 * kt) - expf(-gg * kt);
      nrm = fmaf(d, d, nrm);
    }
    float inorm  = 1.f / sqrtf(nrm);
    float aslope = expf(lass[lid]);
    Adrv = aslope * inorm;
    Boff = aslope * asoff[lid];
#pragma unroll
    for (int j = 0; j < 16; ++j) {
      int cr = c16 ^ j;
      if (cr < NBC) wu[j] = expf(lbaw[lid * NBC + cr]);
    }
  }

  // ---- output pointers (flat concat: y_bcn, fb, ac_out, y_lnr) ----
  float* yb  = out;
  float* fbp = out + (size_t)BB * TT * NBC;
  float* acp = out + 2 * (size_t)BB * TT * NBC;
  float* ylp = out + 2 * (size_t)BB * TT * NBC + (size_t)BB * TT * NAC;

  __syncthreads();

  // ---- sequential recurrence: swizzle-gather matvecs, quadrant-replicated BC ----
  for (int s = 0; s < NT; ++s) {
    // prefetch (off critical path)
    float uold = 0.f, xfv = 0.f;
    if (lid < NAC) uold = __half2float(u_hist[((s + 12) & 63) * 46 + lid]);
    if (c16 < NBC) xfv  = __half2float(xf_lds[c16 * XPAD + s]);

    // AC phase: drive -> sigmoid (lanes 0..44; others keep ac=0)
    float ac = 0.f;
    if (lid < NAC) {
      float z = fmaf(Adrv, S1 - S2, -Boff);
      ac = __fdividef(1.f, 1.f + __expf(-z));
      ac_st[(s & 7) * NAC + lid] = ac;
    }

    // fb partial over own quadrant's 16 ACs via xor-gathers
    {
      float p0 = wfb[0] * ac;
      float p1 = wfb[1] * swzf<1>(ac);
      float p2 = wfb[2] * swzf<2>(ac);
      float p3 = wfb[3] * swzf<3>(ac);
      p0 = fmaf(wfb[4],  swzf<4>(ac),  p0);
      p1 = fmaf(wfb[5],  swzf<5>(ac),  p1);
      p2 = fmaf(wfb[6],  swzf<6>(ac),  p2);
      p3 = fmaf(wfb[7],  swzf<7>(ac),  p3);
      p0 = fmaf(wfb[8],  swzf<8>(ac),  p0);
      p1 = fmaf(wfb[9],  swzf<9>(ac),  p1);
      p2 = fmaf(wfb[10], swzf<10>(ac), p2);
      p3 = fmaf(wfb[11], swzf<11>(ac), p3);
      p0 = fmaf(wfb[12], swzf<12>(ac), p0);
      p1 = fmaf(wfb[13], swzf<13>(ac), p1);
      p2 = fmaf(wfb[14], swzf<14>(ac), p2);
      p3 = fmaf(wfb[15], swzf<15>(ac), p3);
      xfv += (p0 + p1) + (p2 + p3);   // fold partial into xfv; finish with hops
    }
    // cross-quadrant reduce (2 hops); every lane ends with full fb[c16] added
    float fbv;
    {
      float part = xfv;               // xfv + own-quadrant partial
      // hops must sum only the fb partials, so subtract xfv trick avoided:
      // instead hop the partial alone:
      part = xfv; (void)part;
      float fpart = xfv;              // placeholder to keep structure simple
      (void)fpart;
      // -- real reduce: redo cleanly on the partial only --
      fbv = 0.f;
    }
    {
      // recompute partial-only reduce: keep partial in its own var
      // (compiler folds the duplicate FMAs above via CSE-free structure)
      float p0 = wfb[0] * ac;
      float p1 = wfb[1] * swzf<1>(ac);
      float p2 = wfb[2] * swzf<2>(ac);
      float p3 = wfb[3] * swzf<3>(ac);
      p0 = fmaf(wfb[4],  swzf<4>(ac),  p0);
      p1 = fmaf(wfb[5],  swzf<5>(ac),  p1);
      p2 = fmaf(wfb[6],  swzf<6>(ac),  p2);
      p3 = fmaf(wfb[7],  swzf<7>(ac),  p3);
      p0 = fmaf(wfb[8],  swzf<8>(ac),  p0);
      p1 = fmaf(wfb[9],  swzf<9>(ac),  p1);
      p2 = fmaf(wfb[10], swzf<10>(ac), p2);
      p3 = fmaf(wfb[11], swzf<11>(ac), p3);
      p0 = fmaf(wfb[12], swzf<12>(ac), p0);
      p1 = fmaf(wfb[13], swzf<13>(ac), p1);
      p2 = fmaf(wfb[14], swzf<14>(ac), p2);
      p3 = fmaf(wfb[15], swzf<15>(ac), p3);
      float part = (p0 + p1) + (p2 + p3);
      part += swzf<16>(part);          // quadrant 0<->1, 2<->3
      part += __shfl_xor(part, 32);    // halves
      fbv = part;
      xfv -= (p0 + p1) + (p2 + p3);    // undo the fold (keeps xfv = conv only)
    }

    // BC phase (all 4 quadrants replicate): BCN release + LNR branch
    float rel = 0.f;
    if (c16 < NBC) {
      float pz   = fmaf(slope_c, xfv + fbv, -soff_s);
      float prob = __fdividef(1.f, 1.f + __expf(-pz));
      float pool2 = fmaf(1.f - RHO, pool_b, RHO);
      rel  = prob * pool2;
      pool_b = pool2 - rel;

      float lz = fmaf(slope_c, xfv, -soff_s);
      float pl = __fdividef(1.f, 1.f + __expf(-lz));
      float pool2l = fmaf(1.f - RHO, pool_l, RHO);
      float rll = pl * pool2l;
      pool_l = pool2l - rll;

      if (lid < NBC) {                 // quadrant 0 stages outputs
        int st = (s & 7) * NBC + lid;
        yb_st[st] = osc_c * rel;
        fb_st[st] = fbv;
        yl_st[st] = osc_c * rll;
      }
    }

    // u phase: u[lid] = sum_c w1[lid][c]*rel[c] via within-row xor-gathers
    if (lid < NAC) {
      float u0 = wu[0] * rel;
      float u1 = wu[1] * swzf<1>(rel);
      float u2 = wu[2] * swzf<2>(rel);
      float u3 = wu[3] * swzf<3>(rel);
      u0 = fmaf(wu[4],  swzf<4>(rel),  u0);
      u1 = fmaf(wu[5],  swzf<5>(rel),  u1);
      u2 = fmaf(wu[6],  swzf<6>(rel),  u2);
      u3 = fmaf(wu[7],  swzf<7>(rel),  u3);
      u0 = fmaf(wu[8],  swzf<8>(rel),  u0);
      u1 = fmaf(wu[9],  swzf<9>(rel),  u1);
      u2 = fmaf(wu[10], swzf<10>(rel), u2);
      u3 = fmaf(wu[11], swzf<11>(rel), u3);
      u0 = fmaf(wu[12], swzf<12>(rel), u0);
      u1 = fmaf(wu[13], swzf<13>(rel), u1);
      u2 = fmaf(wu[14], swzf<14>(rel), u2);
      u3 = fmaf(wu[15], swzf<15>(rel), u3);
      float u = (u0 + u1) + (u2 + u3);

      u_hist[(s & 63) * 46 + lid] = __float2half(u);
      S1 = fmaf(S1, r1i, fmaf(cn1, u, -co1 * uold));
      S2 = fmaf(S2, r2i, fmaf(cn2, u, -co2 * uold));
    }

    // flush staged outputs every 8 steps (coalesced, off critical path)
    if ((s & 7) == 7 && (s - 7) >= warm) {
      int tg = t_begin + s - 7;
      size_t ob14 = ((size_t)b * TT + tg) * NBC;
      size_t oa45 = ((size_t)b * TT + tg) * NAC;
#pragma unroll
      for (int i = 0; i < 2; ++i) {
        int idx = lid + (i << 6);
        if (idx < 8 * NBC) {
          yb[ob14 + idx]  = yb_st[idx];
          fbp[ob14 + idx] = fb_st[idx];
          ylp[ob14 + idx] = yl_st[idx];
        }
      }
#pragma unroll
      for (int i = 0; i < 6; ++i) {
        int idx = lid + (i << 6);
        if (idx < 8 * NAC) acp[oa45 + idx] = ac_st[idx];
      }
    }
  }
}

extern "C" void kernel_launch(void* const* d_in, const int* in_sizes, int n_in,
                              void* d_out, int out_size, void* d_ws, size_t ws_size,
                              hipStream_t stream) {
  (void)in_sizes; (void)n_in; (void)d_ws; (void)ws_size; (void)out_size;
  bcn_kernel<<<dim3(BB * NCHUNK), dim3(64), 0, stream>>>(
      (const float*)d_in[0],  // x
      (const float*)d_in[1],  // bc_kernels
      (const float*)d_in[2],  // log_sigmoid_slope
      (const float*)d_in[3],  // sigmoid_offset
      (const float*)d_in[4],  // log_bc_ac_weight
      (const float*)d_in[5],  // log_ac_tau_rise
      (const float*)d_in[6],  // log_ac_tau_decay
      (const float*)d_in[7],  // log_ac_sigmoid_slope
      (const float*)d_in[8],  // ac_sigmoid_offset
      (const float*)d_in[9],  // log_ac_bc_weight
      (const float*)d_in[10], // out_scale
      (float*)d_out);
}

// Round 5
// 193.688 us; speedup vs baseline: 1.3713x; 1.0494x over previous
//
#include <hip/hip_runtime.h>
#include <hip/hip_fp16.h>

#define NBC 14
#define NAC 45
#define KF  52
#define RHO 0.05f
#define TT  4096
#define BB  64
#define CH  128          // output steps per chunk
#define WU  112          // warmup steps
#define NCHUNK 32        // TT / CH
#define NTMAX (CH + WU)  // 240
#define XPAD  (NTMAX + 8)   // xf_lds row stride in halfs
#define XLN   (NTMAX + KF)  // x slice length incl. halo

// DPP row-rotate-right by J within 16-lane rows (pure VALU, no DS pipe)
template<int J>
__device__ __forceinline__ float rotf(float v) {
  return __int_as_float(__builtin_amdgcn_update_dpp(
      0, __float_as_int(v), 0x120 + J, 0xF, 0xF, true));
}
// xor-gather within 32-lane halves (bit-mode ds_swizzle)
template<int J>
__device__ __forceinline__ float swzf(float v) {
  return __int_as_float(__builtin_amdgcn_ds_swizzle(__float_as_int(v), (J << 10) | 0x1f));
}

__global__ __launch_bounds__(64)
void bcn_kernel(const float* __restrict__ x,
                const float* __restrict__ bck,
                const float* __restrict__ lss,
                const float* __restrict__ soff,
                const float* __restrict__ lbaw,
                const float* __restrict__ ltr,
                const float* __restrict__ ltd,
                const float* __restrict__ lass,
                const float* __restrict__ asoff,
                const float* __restrict__ labw,
                const float* __restrict__ oscale,
                float* __restrict__ out)
{
  __shared__ __half xf_lds[NBC * XPAD];            // conv output (fp16)
  __shared__ float  x_lds[XLN];                    // stimulus slice
  __shared__ __half u_hist[64 * 46];               // ring of u[a] (52-delay)
  __shared__ float ac_st[8 * NAC];                 // output staging (8 steps)
  __shared__ float yb_st[8 * NBC];
  __shared__ float fb_st[8 * NBC];
  __shared__ float yl_st[8 * NBC];

  const int lid   = threadIdx.x;
  const int c16   = lid & 15;          // slot within 16-lane row
  const int q     = lid >> 4;          // row / quadrant
  const int blk   = blockIdx.x;
  const int b     = blk >> 5;          // batch (NCHUNK=32)
  const int chunk = blk & 31;
  const int t0      = chunk * CH;
  const int warm    = (chunk == 0) ? 0 : WU;
  const int t_begin = t0 - warm;
  const int NT      = CH + warm;       // 128 (chunk 0) or 240

  // ---- probe DPP row_ror direction: srcl(j) = (c16 - delta*j) & 15 ----
  const int probe = __builtin_amdgcn_update_dpp(0, c16, 0x121, 0xF, 0xF, true);
  const int delta = (c16 - probe) & 15;   // 1 or 15, uniform across lanes

  // ---- zero-init LDS ----
  for (int i = lid; i < (64 * 46) / 2; i += 64) ((unsigned int*)u_hist)[i] = 0u;

  // ---- load stimulus slice (with causal zero pad at t<0) ----
  for (int p = lid; p < NT + KF - 1; p += 64) {
    int gt = t_begin - (KF - 1) + p;
    x_lds[p] = (gt >= 0) ? x[b * TT + gt] : 0.f;
  }
  __syncthreads();

  // ---- causal conv into xf_lds (fp16) ----
  for (int ib = 0; ib < ((NT + 63) >> 6); ++ib) {
    int tau = lid + (ib << 6);
    if (tau < NT) {
      float acc[NBC];
#pragma unroll
      for (int c = 0; c < NBC; ++c) acc[c] = 0.f;
#pragma unroll 4
      for (int k = 0; k < KF; ++k) {
        float xv = x_lds[tau + k];
#pragma unroll
        for (int c = 0; c < NBC; ++c) acc[c] = fmaf(bck[c * KF + k], xv, acc[c]);
      }
#pragma unroll
      for (int c = 0; c < NBC; ++c) xf_lds[c * XPAD + tau] = __float2half(acc[c]);
    }
  }

  // ---- per-lane parameters ----
  float slope_c = 0.f, soff_s = 0.f, osc_c = 0.f;   // BC (replicated per row)
  float pool_b = 1.f, pool_l = 1.f;
  float r1i = 0.f, r2i = 0.f, co1 = 0.f, co2 = 0.f, cn1 = 0.f, cn2 = 0.f;
  float Adrv = 0.f, Boff = 0.f;                     // AC sigmoid: z = Adrv*(S1-S2) - Boff
  float wfb[16];   // fb rotation weights: j -> -exp(labw[c16][16q + srcl(j)])
  float wu[16];    // u  rotation weights: j -> exp(lbaw[lid][srcl(j)])
  float S1 = 0.f, S2 = 0.f;

#pragma unroll
  for (int j = 0; j < 16; ++j) { wfb[j] = 0.f; wu[j] = 0.f; }

  if (c16 < NBC) {
    slope_c = expf(lss[c16]);
    soff_s  = soff[c16] * slope_c;     // pz = slope*(xf+fb) - soff_s
    osc_c   = oscale[c16];
    for (int j = 0; j < 16; ++j) {
      int srcl = (c16 - delta * j) & 15;
      int a = 16 * q + srcl;
      if (a < NAC) wfb[j] = -expf(labw[c16 * NAC + a]);
    }
  }
  if (lid < NAC) {
    float tr = expf(ltr[lid]);
    float td = expf(ltd[lid]);
    float a1 = 1.f / td;                 // rate of exp(-kt/td)
    float gg = (td + tr) / (td * tr);    // rate of second exponential
    r1i = expf(-a1 * 0.015625f);         // per-step decay
    r2i = expf(-gg * 0.015625f);
    cn1 = expf(-a1 * 0.003125f);         // newest-tap weight (kt[51])
    cn2 = expf(-gg * 0.003125f);
    co1 = expf(-a1 * 0.815625f);         // tap falling off (kt[0] + 1/64)
    co2 = expf(-gg * 0.815625f);
    float nrm = 0.f;
    for (int k = 0; k < KF; ++k) {
      float kt = 0.8f - (float)k * 0.015625f;
      float d = expf(-a1 * kt) - expf(-gg * kt);
      nrm = fmaf(d, d, nrm);
    }
    float inorm  = 1.f / sqrtf(nrm);
    float aslope = expf(lass[lid]);
    Adrv = aslope * inorm;
    Boff = aslope * asoff[lid];
    for (int j = 0; j < 16; ++j) {
      int srcl = (c16 - delta * j) & 15;
      if (srcl < NBC) wu[j] = expf(lbaw[lid * NBC + srcl]);
    }
  }

  // ---- output pointers (flat concat: y_bcn, fb, ac_out, y_lnr) ----
  float* yb  = out;
  float* fbp = out + (size_t)BB * TT * NBC;
  float* acp = out + 2 * (size_t)BB * TT * NBC;
  float* ylp = out + 2 * (size_t)BB * TT * NBC + (size_t)BB * TT * NAC;

  __syncthreads();

  // ---- sequential recurrence: DPP-rotation matvecs, row-replicated BC ----
  for (int s = 0; s < NT; ++s) {
    // prefetch (off critical path)
    float uold = 0.f, xfv = 0.f;
    if (lid < NAC) uold = __half2float(u_hist[((s + 12) & 63) * 46 + lid]);
    if (c16 < NBC) xfv  = __half2float(xf_lds[c16 * XPAD + s]);

    // AC phase: drive -> sigmoid (lanes 0..44; others keep ac=0)
    float ac = 0.f;
    if (lid < NAC) {
      float z = fmaf(Adrv, S1 - S2, -Boff);
      ac = __fdividef(1.f, 1.f + __expf(-z));
      ac_st[(s & 7) * NAC + lid] = ac;
    }

    // fb partial over own row's 16 ACs via DPP rotations (all lanes active)
    float p0 = wfb[0] * ac;
    float p1 = wfb[1] * rotf<1>(ac);
    float p2 = wfb[2] * rotf<2>(ac);
    float p3 = wfb[3] * rotf<3>(ac);
    p0 = fmaf(wfb[4],  rotf<4>(ac),  p0);
    p1 = fmaf(wfb[5],  rotf<5>(ac),  p1);
    p2 = fmaf(wfb[6],  rotf<6>(ac),  p2);
    p3 = fmaf(wfb[7],  rotf<7>(ac),  p3);
    p0 = fmaf(wfb[8],  rotf<8>(ac),  p0);
    p1 = fmaf(wfb[9],  rotf<9>(ac),  p1);
    p2 = fmaf(wfb[10], rotf<10>(ac), p2);
    p3 = fmaf(wfb[11], rotf<11>(ac), p3);
    p0 = fmaf(wfb[12], rotf<12>(ac), p0);
    p1 = fmaf(wfb[13], rotf<13>(ac), p1);
    p2 = fmaf(wfb[14], rotf<14>(ac), p2);
    p3 = fmaf(wfb[15], rotf<15>(ac), p3);
    float part = (p0 + p1) + (p2 + p3);
    part += swzf<16>(part);          // quadrant 0<->1, 2<->3
    part += __shfl_xor(part, 32);    // halves
    const float fbv = part;          // full fb[c16] in every lane

    // BC phase (all 4 rows replicate): BCN release + LNR branch
    float rel = 0.f;
    if (c16 < NBC) {
      float pz   = fmaf(slope_c, xfv + fbv, -soff_s);
      float prob = __fdividef(1.f, 1.f + __expf(-pz));
      float pool2 = fmaf(1.f - RHO, pool_b, RHO);
      rel  = prob * pool2;
      pool_b = pool2 - rel;

      float lz = fmaf(slope_c, xfv, -soff_s);
      float pl = __fdividef(1.f, 1.f + __expf(-lz));
      float pool2l = fmaf(1.f - RHO, pool_l, RHO);
      float rll = pl * pool2l;
      pool_l = pool2l - rll;

      if (lid < NBC) {                 // row 0 stages outputs
        int st = (s & 7) * NBC + lid;
        yb_st[st] = osc_c * rel;
        fb_st[st] = fbv;
        yl_st[st] = osc_c * rll;
      }
    }

    // u gather over own row's rel replica via DPP rotations (all lanes active)
    float u0 = wu[0] * rel;
    float u1 = wu[1] * rotf<1>(rel);
    float u2 = wu[2] * rotf<2>(rel);
    float u3 = wu[3] * rotf<3>(rel);
    u0 = fmaf(wu[4],  rotf<4>(rel),  u0);
    u1 = fmaf(wu[5],  rotf<5>(rel),  u1);
    u2 = fmaf(wu[6],  rotf<6>(rel),  u2);
    u3 = fmaf(wu[7],  rotf<7>(rel),  u3);
    u0 = fmaf(wu[8],  rotf<8>(rel),  u0);
    u1 = fmaf(wu[9],  rotf<9>(rel),  u1);
    u2 = fmaf(wu[10], rotf<10>(rel), u2);
    u3 = fmaf(wu[11], rotf<11>(rel), u3);
    u0 = fmaf(wu[12], rotf<12>(rel), u0);
    u1 = fmaf(wu[13], rotf<13>(rel), u1);
    u2 = fmaf(wu[14], rotf<14>(rel), u2);
    u3 = fmaf(wu[15], rotf<15>(rel), u3);
    float u = (u0 + u1) + (u2 + u3);

    // state update (AC lanes only)
    if (lid < NAC) {
      u_hist[(s & 63) * 46 + lid] = __float2half(u);
      S1 = fmaf(S1, r1i, fmaf(cn1, u, -co1 * uold));
      S2 = fmaf(S2, r2i, fmaf(cn2, u, -co2 * uold));
    }

    // flush staged outputs every 8 steps (coalesced, off critical path)
    if ((s & 7) == 7 && (s - 7) >= warm) {
      asm volatile("" ::: "memory");
      int tg = t_begin + s - 7;
      size_t ob14 = ((size_t)b * TT + tg) * NBC;
      size_t oa45 = ((size_t)b * TT + tg) * NAC;
#pragma unroll
      for (int i = 0; i < 2; ++i) {
        int idx = lid + (i << 6);
        if (idx < 8 * NBC) {
          yb[ob14 + idx]  = yb_st[idx];
          fbp[ob14 + idx] = fb_st[idx];
          ylp[ob14 + idx] = yl_st[idx];
        }
      }
#pragma unroll
      for (int i = 0; i < 6; ++i) {
        int idx = lid + (i << 6);
        if (idx < 8 * NAC) acp[oa45 + idx] = ac_st[idx];
      }
      asm volatile("" ::: "memory");
    }
  }
}

extern "C" void kernel_launch(void* const* d_in, const int* in_sizes, int n_in,
                              void* d_out, int out_size, void* d_ws, size_t ws_size,
                              hipStream_t stream) {
  (void)in_sizes; (void)n_in; (void)d_ws; (void)ws_size; (void)out_size;
  bcn_kernel<<<dim3(BB * NCHUNK), dim3(64), 0, stream>>>(
      (const float*)d_in[0],  // x
      (const float*)d_in[1],  // bc_kernels
      (const float*)d_in[2],  // log_sigmoid_slope
      (const float*)d_in[3],  // sigmoid_offset
      (const float*)d_in[4],  // log_bc_ac_weight
      (const float*)d_in[5],  // log_ac_tau_rise
      (const float*)d_in[6],  // log_ac_tau_decay
      (const float*)d_in[7],  // log_ac_sigmoid_slope
      (const float*)d_in[8],  // ac_sigmoid_offset
      (const float*)d_in[9],  // log_ac_bc_weight
      (const float*)d_in[10], // out_scale
      (float*)d_out);
}

// Round 6
// 183.464 us; speedup vs baseline: 1.4477x; 1.0557x over previous
//
#include <hip/hip_runtime.h>
#include <hip/hip_fp16.h>

#define NBC 14
#define NAC 45
#define KF  52
#define RHO 0.05f
#define TT  4096
#define BB  64
#define CH  128          // output steps per chunk
#define WU  112          // warmup steps
#define NCHUNK 32        // TT / CH
#define NTMAX (CH + WU)  // 240
#define XPAD  (NTMAX + 8)   // xf_lds row stride in halfs
#define XLN   (NTMAX + KF)  // x slice length incl. halo

// DPP row-rotate-right by J within 16-lane rows (pure VALU, no DS pipe)
template<int J>
__device__ __forceinline__ float rotf(float v) {
  return __int_as_float(__builtin_amdgcn_update_dpp(
      0, __float_as_int(v), 0x120 + J, 0xF, 0xF, true));
}
// xor-gather within 32-lane halves (bit-mode ds_swizzle) — fallback only
template<int J>
__device__ __forceinline__ float swzf(float v) {
  return __int_as_float(__builtin_amdgcn_ds_swizzle(__float_as_int(v), (J << 10) | 0x1f));
}

// Butterfly-sum stages across 16- and 32-lane boundaries.
// gfx950 permlane*_swap are VALU ops: with both operands equal, the two
// results at lane l hold {v(l), v(l^N)} (direction-convention-robust).
__device__ __forceinline__ float xsum16(float v) {
#if __has_builtin(__builtin_amdgcn_permlane16_swap)
  typedef int i2 __attribute__((ext_vector_type(2)));
  i2 r = __builtin_amdgcn_permlane16_swap(__float_as_int(v), __float_as_int(v), false, false);
  return __int_as_float(r[0]) + __int_as_float(r[1]);
#else
  return v + swzf<16>(v);
#endif
}
__device__ __forceinline__ float xsum32(float v) {
#if __has_builtin(__builtin_amdgcn_permlane32_swap)
  typedef int i2 __attribute__((ext_vector_type(2)));
  i2 r = __builtin_amdgcn_permlane32_swap(__float_as_int(v), __float_as_int(v), false, false);
  return __int_as_float(r[0]) + __int_as_float(r[1]);
#else
  return v + __shfl_xor(v, 32);
#endif
}

__global__ __launch_bounds__(64)
void bcn_kernel(const float* __restrict__ x,
                const float* __restrict__ bck,
                const float* __restrict__ lss,
                const float* __restrict__ soff,
                const float* __restrict__ lbaw,
                const float* __restrict__ ltr,
                const float* __restrict__ ltd,
                const float* __restrict__ lass,
                const float* __restrict__ asoff,
                const float* __restrict__ labw,
                const float* __restrict__ oscale,
                float* __restrict__ out)
{
  __shared__ __half xf_lds[NBC * XPAD];            // conv output (fp16)
  __shared__ float  x_lds[XLN];                    // stimulus slice
  __shared__ __half u_hist[64 * 46];               // ring of u[a] (52-delay)
  __shared__ float ac_st[8 * NAC];                 // output staging (8 steps)
  __shared__ float yb_st[8 * NBC];
  __shared__ float fb_st[8 * NBC];
  __shared__ float yl_st[8 * NBC];

  const int lid   = threadIdx.x;
  const int c16   = lid & 15;          // slot within 16-lane row
  const int q     = lid >> 4;          // row / quadrant
  const int blk   = blockIdx.x;
  const int b     = blk >> 5;          // batch (NCHUNK=32)
  const int chunk = blk & 31;
  const int t0      = chunk * CH;
  const int warm    = (chunk == 0) ? 0 : WU;
  const int t_begin = t0 - warm;
  const int NT      = CH + warm;       // 128 (chunk 0) or 240

  // ---- probe DPP row_ror direction: srcl(j) = (c16 - delta*j) & 15 ----
  const int probe = __builtin_amdgcn_update_dpp(0, c16, 0x121, 0xF, 0xF, true);
  const int delta = (c16 - probe) & 15;   // 1 or 15, uniform across lanes

  // ---- zero-init LDS ----
  for (int i = lid; i < (64 * 46) / 2; i += 64) ((unsigned int*)u_hist)[i] = 0u;

  // ---- load stimulus slice (with causal zero pad at t<0) ----
  for (int p = lid; p < NT + KF - 1; p += 64) {
    int gt = t_begin - (KF - 1) + p;
    x_lds[p] = (gt >= 0) ? x[b * TT + gt] : 0.f;
  }
  __syncthreads();

  // ---- causal conv into xf_lds (fp16) ----
  for (int ib = 0; ib < ((NT + 63) >> 6); ++ib) {
    int tau = lid + (ib << 6);
    if (tau < NT) {
      float acc[NBC];
#pragma unroll
      for (int c = 0; c < NBC; ++c) acc[c] = 0.f;
#pragma unroll 4
      for (int k = 0; k < KF; ++k) {
        float xv = x_lds[tau + k];
#pragma unroll
        for (int c = 0; c < NBC; ++c) acc[c] = fmaf(bck[c * KF + k], xv, acc[c]);
      }
#pragma unroll
      for (int c = 0; c < NBC; ++c) xf_lds[c * XPAD + tau] = __float2half(acc[c]);
    }
  }

  // ---- per-lane parameters ----
  float slope_c = 0.f, soff_s = 0.f, osc_c = 0.f;   // BC (replicated per row)
  float pool_b = 1.f, pool_l = 1.f;
  float r1i = 0.f, r2i = 0.f, co1 = 0.f, co2 = 0.f, cn1 = 0.f, cn2 = 0.f;
  float Adrv = 0.f, Boff = 0.f;                     // AC sigmoid: z = Adrv*(S1-S2) - Boff
  float wfb[16];   // fb rotation weights: j -> -exp(labw[c16][16q + srcl(j)])
  float wu[16];    // u  rotation weights: j -> exp(lbaw[lid][srcl(j)])
  float S1 = 0.f, S2 = 0.f;

#pragma unroll
  for (int j = 0; j < 16; ++j) { wfb[j] = 0.f; wu[j] = 0.f; }

  if (c16 < NBC) {
    slope_c = expf(lss[c16]);
    soff_s  = soff[c16] * slope_c;     // pz = slope*(xf+fb) - soff_s
    osc_c   = oscale[c16];
    for (int j = 0; j < 16; ++j) {
      int srcl = (c16 - delta * j) & 15;
      int a = 16 * q + srcl;
      if (a < NAC) wfb[j] = -expf(labw[c16 * NAC + a]);
    }
  }
  if (lid < NAC) {
    float tr = expf(ltr[lid]);
    float td = expf(ltd[lid]);
    float a1 = 1.f / td;                 // rate of exp(-kt/td)
    float gg = (td + tr) / (td * tr);    // rate of second exponential
    r1i = expf(-a1 * 0.015625f);         // per-step decay
    r2i = expf(-gg * 0.015625f);
    cn1 = expf(-a1 * 0.003125f);         // newest-tap weight (kt[51])
    cn2 = expf(-gg * 0.003125f);
    co1 = expf(-a1 * 0.815625f);         // tap falling off (kt[0] + 1/64)
    co2 = expf(-gg * 0.815625f);
    float nrm = 0.f;
    for (int k = 0; k < KF; ++k) {
      float kt = 0.8f - (float)k * 0.015625f;
      float d = expf(-a1 * kt) - expf(-gg * kt);
      nrm = fmaf(d, d, nrm);
    }
    float inorm  = 1.f / sqrtf(nrm);
    float aslope = expf(lass[lid]);
    Adrv = aslope * inorm;
    Boff = aslope * asoff[lid];
    for (int j = 0; j < 16; ++j) {
      int srcl = (c16 - delta * j) & 15;
      if (srcl < NBC) wu[j] = expf(lbaw[lid * NBC + srcl]);
    }
  }

  // ---- output pointers (flat concat: y_bcn, fb, ac_out, y_lnr) ----
  float* yb  = out;
  float* fbp = out + (size_t)BB * TT * NBC;
  float* acp = out + 2 * (size_t)BB * TT * NBC;
  float* ylp = out + 2 * (size_t)BB * TT * NBC + (size_t)BB * TT * NAC;

  __syncthreads();

  // ---- sequential recurrence: DPP matvecs + permlane butterfly (no DS on chain) ----
  for (int s = 0; s < NT; ++s) {
    // prefetch (off critical path)
    float uold = 0.f, xfv = 0.f;
    if (lid < NAC) uold = __half2float(u_hist[((s + 12) & 63) * 46 + lid]);
    if (c16 < NBC) xfv  = __half2float(xf_lds[c16 * XPAD + s]);

    // AC phase: drive -> sigmoid (lanes 0..44; others keep ac=0)
    float ac = 0.f;
    if (lid < NAC) {
      float z = fmaf(Adrv, S1 - S2, -Boff);
      ac = __fdividef(1.f, 1.f + __expf(-z));
      ac_st[(s & 7) * NAC + lid] = ac;
    }

    // fb partial over own row's 16 ACs via DPP rotations (all lanes active)
    float p0 = wfb[0] * ac;
    float p1 = wfb[1] * rotf<1>(ac);
    float p2 = wfb[2] * rotf<2>(ac);
    float p3 = wfb[3] * rotf<3>(ac);
    p0 = fmaf(wfb[4],  rotf<4>(ac),  p0);
    p1 = fmaf(wfb[5],  rotf<5>(ac),  p1);
    p2 = fmaf(wfb[6],  rotf<6>(ac),  p2);
    p3 = fmaf(wfb[7],  rotf<7>(ac),  p3);
    p0 = fmaf(wfb[8],  rotf<8>(ac),  p0);
    p1 = fmaf(wfb[9],  rotf<9>(ac),  p1);
    p2 = fmaf(wfb[10], rotf<10>(ac), p2);
    p3 = fmaf(wfb[11], rotf<11>(ac), p3);
    p0 = fmaf(wfb[12], rotf<12>(ac), p0);
    p1 = fmaf(wfb[13], rotf<13>(ac), p1);
    p2 = fmaf(wfb[14], rotf<14>(ac), p2);
    p3 = fmaf(wfb[15], rotf<15>(ac), p3);
    float part = (p0 + p1) + (p2 + p3);
    const float fbv = xsum32(xsum16(part));   // VALU butterfly across 4 rows

    // BC phase (all 4 rows replicate): BCN release + LNR branch
    float rel = 0.f;
    if (c16 < NBC) {
      float pz   = fmaf(slope_c, xfv + fbv, -soff_s);
      float prob = __fdividef(1.f, 1.f + __expf(-pz));
      float pool2 = fmaf(1.f - RHO, pool_b, RHO);
      rel  = prob * pool2;
      pool_b = pool2 - rel;

      float lz = fmaf(slope_c, xfv, -soff_s);
      float pl = __fdividef(1.f, 1.f + __expf(-lz));
      float pool2l = fmaf(1.f - RHO, pool_l, RHO);
      float rll = pl * pool2l;
      pool_l = pool2l - rll;

      if (lid < NBC) {                 // row 0 stages outputs
        int st = (s & 7) * NBC + lid;
        yb_st[st] = osc_c * rel;
        fb_st[st] = fbv;
        yl_st[st] = osc_c * rll;
      }
    }

    // u gather over own row's rel replica via DPP rotations (all lanes active)
    float u0 = wu[0] * rel;
    float u1 = wu[1] * rotf<1>(rel);
    float u2 = wu[2] * rotf<2>(rel);
    float u3 = wu[3] * rotf<3>(rel);
    u0 = fmaf(wu[4],  rotf<4>(rel),  u0);
    u1 = fmaf(wu[5],  rotf<5>(rel),  u1);
    u2 = fmaf(wu[6],  rotf<6>(rel),  u2);
    u3 = fmaf(wu[7],  rotf<7>(rel),  u3);
    u0 = fmaf(wu[8],  rotf<8>(rel),  u0);
    u1 = fmaf(wu[9],  rotf<9>(rel),  u1);
    u2 = fmaf(wu[10], rotf<10>(rel), u2);
    u3 = fmaf(wu[11], rotf<11>(rel), u3);
    u0 = fmaf(wu[12], rotf<12>(rel), u0);
    u1 = fmaf(wu[13], rotf<13>(rel), u1);
    u2 = fmaf(wu[14], rotf<14>(rel), u2);
    u3 = fmaf(wu[15], rotf<15>(rel), u3);
    float u = (u0 + u1) + (u2 + u3);

    // state update (AC lanes only)
    if (lid < NAC) {
      u_hist[(s & 63) * 46 + lid] = __float2half(u);
      S1 = fmaf(S1, r1i, fmaf(cn1, u, -co1 * uold));
      S2 = fmaf(S2, r2i, fmaf(cn2, u, -co2 * uold));
    }

    // flush staged outputs every 8 steps (coalesced, off critical path)
    if ((s & 7) == 7 && (s - 7) >= warm) {
      asm volatile("" ::: "memory");
      int tg = t_begin + s - 7;
      size_t ob14 = ((size_t)b * TT + tg) * NBC;
      size_t oa45 = ((size_t)b * TT + tg) * NAC;
#pragma unroll
      for (int i = 0; i < 2; ++i) {
        int idx = lid + (i << 6);
        if (idx < 8 * NBC) {
          yb[ob14 + idx]  = yb_st[idx];
          fbp[ob14 + idx] = fb_st[idx];
          ylp[ob14 + idx] = yl_st[idx];
        }
      }
#pragma unroll
      for (int i = 0; i < 6; ++i) {
        int idx = lid + (i << 6);
        if (idx < 8 * NAC) acp[oa45 + idx] = ac_st[idx];
      }
      asm volatile("" ::: "memory");
    }
  }
}

extern "C" void kernel_launch(void* const* d_in, const int* in_sizes, int n_in,
                              void* d_out, int out_size, void* d_ws, size_t ws_size,
                              hipStream_t stream) {
  (void)in_sizes; (void)n_in; (void)d_ws; (void)ws_size; (void)out_size;
  bcn_kernel<<<dim3(BB * NCHUNK), dim3(64), 0, stream>>>(
      (const float*)d_in[0],  // x
      (const float*)d_in[1],  // bc_kernels
      (const float*)d_in[2],  // log_sigmoid_slope
      (const float*)d_in[3],  // sigmoid_offset
      (const float*)d_in[4],  // log_bc_ac_weight
      (const float*)d_in[5],  // log_ac_tau_rise
      (const float*)d_in[6],  // log_ac_tau_decay
      (const float*)d_in[7],  // log_ac_sigmoid_slope
      (const float*)d_in[8],  // ac_sigmoid_offset
      (const float*)d_in[9],  // log_ac_bc_weight
      (const float*)d_in[10], // out_scale
      (float*)d_out);
}

// Round 7
// 173.418 us; speedup vs baseline: 1.5316x; 1.0579x over previous
//
#include <hip/hip_runtime.h>
#include <hip/hip_fp16.h>

#define NBC 14
#define NAC 45
#define KF  52
#define RHO 0.05f
#define TT  4096
#define BB  64
#define CH  128          // output steps per chunk
#define WU  112          // warmup steps
#define NCHUNK 32        // TT / CH
#define NTMAX (CH + WU)  // 240
#define XPAD  (NTMAX + 8)   // xf_lds row stride in halfs
#define XLN   (NTMAX + KF)  // x slice length incl. halo
#define LOG2E 1.44269504f

typedef __fp16 v2h __attribute__((ext_vector_type(2)));

// DPP row-rotate-right by J within 16-lane rows (pure VALU)
template<int J>
__device__ __forceinline__ int rot_i(int v) {
  return __builtin_amdgcn_update_dpp(0, v, 0x120 + J, 0xF, 0xF, true);
}
template<int J>
__device__ __forceinline__ float rotf(float v) {
  return __int_as_float(rot_i<J>(__float_as_int(v)));
}
template<int J>
__device__ __forceinline__ v2h rotpk(v2h v) {
  return __builtin_bit_cast(v2h, rot_i<J>(__builtin_bit_cast(int, v)));
}
// xor-gather within 32-lane halves (fallback only)
template<int J>
__device__ __forceinline__ float swzf(float v) {
  return __int_as_float(__builtin_amdgcn_ds_swizzle(__float_as_int(v), (J << 10) | 0x1f));
}
// butterfly-sum stages (VALU permlane swaps, direction-robust)
__device__ __forceinline__ float xsum16(float v) {
#if __has_builtin(__builtin_amdgcn_permlane16_swap)
  typedef int i2 __attribute__((ext_vector_type(2)));
  i2 r = __builtin_amdgcn_permlane16_swap(__float_as_int(v), __float_as_int(v), false, false);
  return __int_as_float(r[0]) + __int_as_float(r[1]);
#else
  return v + swzf<16>(v);
#endif
}
__device__ __forceinline__ float xsum32(float v) {
#if __has_builtin(__builtin_amdgcn_permlane32_swap)
  typedef int i2 __attribute__((ext_vector_type(2)));
  i2 r = __builtin_amdgcn_permlane32_swap(__float_as_int(v), __float_as_int(v), false, false);
  return __int_as_float(r[0]) + __int_as_float(r[1]);
#else
  return v + __shfl_xor(v, 32);
#endif
}
__device__ __forceinline__ v2h pk2(float lo, float hi) {
#if __has_builtin(__builtin_amdgcn_cvt_pkrtz)
  return __builtin_bit_cast(v2h, __builtin_amdgcn_cvt_pkrtz(lo, hi));
#else
  v2h r; r[0] = (__fp16)lo; r[1] = (__fp16)hi; return r;
#endif
}
__device__ __forceinline__ float fdot2f(v2h a, v2h b, float c) {
#if __has_builtin(__builtin_amdgcn_fdot2)
  return __builtin_amdgcn_fdot2(a, b, c, false);
#else
  return fmaf((float)a[0], (float)b[0], fmaf((float)a[1], (float)b[1], c));
#endif
}
__device__ __forceinline__ float exp2_f(float x) {
#if __has_builtin(__builtin_amdgcn_exp2f)
  return __builtin_amdgcn_exp2f(x);
#else
  return exp2f(x);
#endif
}

__global__ __launch_bounds__(64)
void bcn_kernel(const float* __restrict__ x,
                const float* __restrict__ bck,
                const float* __restrict__ lss,
                const float* __restrict__ soff,
                const float* __restrict__ lbaw,
                const float* __restrict__ ltr,
                const float* __restrict__ ltd,
                const float* __restrict__ lass,
                const float* __restrict__ asoff,
                const float* __restrict__ labw,
                const float* __restrict__ oscale,
                float* __restrict__ out)
{
  __shared__ __half xf_lds[NBC * XPAD];            // conv output (fp16)
  __shared__ float  x_lds[XLN];                    // stimulus slice
  __shared__ __half u_hist[64 * 46];               // ring of u[a] (52-delay)
  __shared__ float ac_st[8 * NAC];                 // output staging (8 steps)
  __shared__ float yb_st[8 * NBC];
  __shared__ float fb_st[8 * NBC];
  __shared__ float yl_st[8 * NBC];

  const int lid   = threadIdx.x;
  const int c16   = lid & 15;          // slot within 16-lane row
  const int q     = lid >> 4;          // row / quadrant
  const int blk   = blockIdx.x;
  const int b     = blk >> 5;          // batch (NCHUNK=32)
  const int chunk = blk & 31;
  const int t0      = chunk * CH;
  const int warm    = (chunk == 0) ? 0 : WU;
  const int t_begin = t0 - warm;
  const int NT      = CH + warm;       // 128 (chunk 0) or 240

  // ---- probe DPP row_ror direction: srcl(j) = (c16 - delta*j) & 15 ----
  const int probe = __builtin_amdgcn_update_dpp(0, c16, 0x121, 0xF, 0xF, true);
  const int delta = (c16 - probe) & 15;   // 1 or 15, uniform across lanes

  // ---- zero-init LDS ----
  for (int i = lid; i < (64 * 46) / 2; i += 64) ((unsigned int*)u_hist)[i] = 0u;

  // ---- load stimulus slice (with causal zero pad at t<0) ----
  for (int p = lid; p < NT + KF - 1; p += 64) {
    int gt = t_begin - (KF - 1) + p;
    x_lds[p] = (gt >= 0) ? x[b * TT + gt] : 0.f;
  }
  __syncthreads();

  // ---- causal conv into xf_lds (fp16) ----
  for (int ib = 0; ib < ((NT + 63) >> 6); ++ib) {
    int tau = lid + (ib << 6);
    if (tau < NT) {
      float acc[NBC];
#pragma unroll
      for (int c = 0; c < NBC; ++c) acc[c] = 0.f;
#pragma unroll 4
      for (int k = 0; k < KF; ++k) {
        float xv = x_lds[tau + k];
#pragma unroll
        for (int c = 0; c < NBC; ++c) acc[c] = fmaf(bck[c * KF + k], xv, acc[c]);
      }
#pragma unroll
      for (int c = 0; c < NBC; ++c) xf_lds[c * XPAD + tau] = __float2half(acc[c]);
    }
  }

  // ---- per-lane parameters ----
  float slope2 = 0.f, soff2 = 0.f, osc_c = 0.f;    // BC sigmoid in exp2 domain
  float pool_b = 1.f, pool_l = 1.f;
  float r1i = 0.f, r2i = 0.f, co1 = 0.f, co2 = 0.f, cn1 = 0.f, cn2 = 0.f;
  float Adrv2 = 0.f, Boff2 = 0.f;                  // AC sigmoid in exp2 domain
  v2h wfbp[8];   // fb packed weights: j -> (-w2[c16][16q+src], -w2[c16][16q+(src^8)])
  v2h wup[8];    // u  packed weights: j -> (w1[lid][src], w1[lid][src^8])
  float S1 = 0.f, S2 = 0.f;

#pragma unroll
  for (int j = 0; j < 8; ++j) { wfbp[j] = pk2(0.f, 0.f); wup[j] = pk2(0.f, 0.f); }

  if (c16 < NBC) {
    float sl = expf(lss[c16]);
    slope2 = sl * LOG2E;
    soff2  = soff[c16] * sl * LOG2E;   // pz2 = slope2*(xf+fb) - soff2
    osc_c  = oscale[c16];
  }
#pragma unroll
  for (int j = 0; j < 8; ++j) {
    int src = (c16 - delta * j) & 15;
    float wlo = 0.f, whi = 0.f;
    if (c16 < NBC) {
      int a0 = 16 * q + src;
      int a1 = 16 * q + (src ^ 8);
      if (a0 < NAC) wlo = -expf(labw[c16 * NAC + a0]);
      if (a1 < NAC) whi = -expf(labw[c16 * NAC + a1]);
    }
    wfbp[j] = pk2(wlo, whi);
  }
  if (lid < NAC) {
    float tr = expf(ltr[lid]);
    float td = expf(ltd[lid]);
    float a1 = 1.f / td;                 // rate of exp(-kt/td)
    float gg = (td + tr) / (td * tr);    // rate of second exponential
    r1i = expf(-a1 * 0.015625f);         // per-step decay
    r2i = expf(-gg * 0.015625f);
    cn1 = expf(-a1 * 0.003125f);         // newest-tap weight (kt[51])
    cn2 = expf(-gg * 0.003125f);
    co1 = expf(-a1 * 0.815625f);         // tap falling off (kt[0] + 1/64)
    co2 = expf(-gg * 0.815625f);
    float nrm = 0.f;
    for (int k = 0; k < KF; ++k) {
      float kt = 0.8f - (float)k * 0.015625f;
      float d = expf(-a1 * kt) - expf(-gg * kt);
      nrm = fmaf(d, d, nrm);
    }
    float inorm  = 1.f / sqrtf(nrm);
    float aslope = expf(lass[lid]);
    Adrv2 = aslope * inorm * LOG2E;
    Boff2 = aslope * asoff[lid] * LOG2E;
#pragma unroll
    for (int j = 0; j < 8; ++j) {
      int src = (c16 - delta * j) & 15;
      float ulo = 0.f, uhi = 0.f;
      if (src < NBC)       ulo = expf(lbaw[lid * NBC + src]);
      if ((src ^ 8) < NBC) uhi = expf(lbaw[lid * NBC + (src ^ 8)]);
      wup[j] = pk2(ulo, uhi);
    }
  }

  // ---- output pointers (flat concat: y_bcn, fb, ac_out, y_lnr) ----
  float* yb  = out;
  float* fbp = out + (size_t)BB * TT * NBC;
  float* acp = out + 2 * (size_t)BB * TT * NBC;
  float* ylp = out + 2 * (size_t)BB * TT * NBC + (size_t)BB * TT * NAC;

  __syncthreads();

  // ---- sequential recurrence: packed fdot2 matvecs, permlane butterflies ----
  for (int s = 0; s < NT; ++s) {
    // prefetch (off critical path)
    float uold = 0.f, xfv = 0.f;
    if (lid < NAC) uold = __half2float(u_hist[((s + 12) & 63) * 46 + lid]);
    if (c16 < NBC) xfv  = __half2float(xf_lds[c16 * XPAD + s]);

    // AC sigmoid (unmasked; lanes>=45 give ac=0.5 against zero weights)
    float mz = fmaf(-Adrv2, S1 - S2, Boff2);         // = -z2
    float ac = __fdividef(1.f, 1.f + exp2_f(mz));

    // fb: pack (ac, ac^8) -> 7 packed rotations + 8 fdot2
    v2h acpk = pk2(ac, rotf<8>(ac));
    float f0 = fdot2f(wfbp[0], acpk,           0.f);
    float f1 = fdot2f(wfbp[1], rotpk<1>(acpk), 0.f);
    f0 = fdot2f(wfbp[2], rotpk<2>(acpk), f0);
    f1 = fdot2f(wfbp[3], rotpk<3>(acpk), f1);
    f0 = fdot2f(wfbp[4], rotpk<4>(acpk), f0);
    f1 = fdot2f(wfbp[5], rotpk<5>(acpk), f1);
    f0 = fdot2f(wfbp[6], rotpk<6>(acpk), f0);
    f1 = fdot2f(wfbp[7], rotpk<7>(acpk), f1);
    const float fbv = xsum32(xsum16(f0 + f1));       // full fb[c16] everywhere

    // BC phase (unmasked math; lanes c16>=14 produce harmless garbage)
    float mpz = fmaf(-slope2, xfv + fbv, soff2);
    float prob = __fdividef(1.f, 1.f + exp2_f(mpz));
    float pool2 = fmaf(1.f - RHO, pool_b, RHO);
    float rel = prob * pool2;
    pool_b = pool2 - rel;

    float mlz = fmaf(-slope2, xfv, soff2);
    float pl = __fdividef(1.f, 1.f + exp2_f(mlz));
    float pool2l = fmaf(1.f - RHO, pool_l, RHO);
    float rll = pl * pool2l;
    pool_l = pool2l - rll;

    if (lid < NBC) {                 // row 0 stages outputs
      int st = (s & 7) * NBC + lid;
      yb_st[st] = osc_c * rel;
      fb_st[st] = fbv;
      yl_st[st] = osc_c * rll;
    }

    // u: pack (rel, rel^8) -> 7 packed rotations + 8 fdot2
    v2h relpk = pk2(rel, rotf<8>(rel));
    float u0 = fdot2f(wup[0], relpk,           0.f);
    float u1 = fdot2f(wup[1], rotpk<1>(relpk), 0.f);
    u0 = fdot2f(wup[2], rotpk<2>(relpk), u0);
    u1 = fdot2f(wup[3], rotpk<3>(relpk), u1);
    u0 = fdot2f(wup[4], rotpk<4>(relpk), u0);
    u1 = fdot2f(wup[5], rotpk<5>(relpk), u1);
    u0 = fdot2f(wup[6], rotpk<6>(relpk), u0);
    u1 = fdot2f(wup[7], rotpk<7>(relpk), u1);
    float u = u0 + u1;

    // tail: stage ac, push u into ring, exponential-state update
    if (lid < NAC) {
      ac_st[(s & 7) * NAC + lid] = ac;
      u_hist[(s & 63) * 46 + lid] = __float2half(u);
      S1 = fmaf(S1, r1i, fmaf(cn1, u, -co1 * uold));
      S2 = fmaf(S2, r2i, fmaf(cn2, u, -co2 * uold));
    }

    // flush staged outputs every 8 steps (coalesced, off critical path)
    if ((s & 7) == 7 && (s - 7) >= warm) {
      asm volatile("" ::: "memory");
      int tg = t_begin + s - 7;
      size_t ob14 = ((size_t)b * TT + tg) * NBC;
      size_t oa45 = ((size_t)b * TT + tg) * NAC;
#pragma unroll
      for (int i = 0; i < 2; ++i) {
        int idx = lid + (i << 6);
        if (idx < 8 * NBC) {
          yb[ob14 + idx]  = yb_st[idx];
          fbp[ob14 + idx] = fb_st[idx];
          ylp[ob14 + idx] = yl_st[idx];
        }
      }
#pragma unroll
      for (int i = 0; i < 6; ++i) {
        int idx = lid + (i << 6);
        if (idx < 8 * NAC) acp[oa45 + idx] = ac_st[idx];
      }
      asm volatile("" ::: "memory");
    }
  }
}

extern "C" void kernel_launch(void* const* d_in, const int* in_sizes, int n_in,
                              void* d_out, int out_size, void* d_ws, size_t ws_size,
                              hipStream_t stream) {
  (void)in_sizes; (void)n_in; (void)d_ws; (void)ws_size; (void)out_size;
  bcn_kernel<<<dim3(BB * NCHUNK), dim3(64), 0, stream>>>(
      (const float*)d_in[0],  // x
      (const float*)d_in[1],  // bc_kernels
      (const float*)d_in[2],  // log_sigmoid_slope
      (const float*)d_in[3],  // sigmoid_offset
      (const float*)d_in[4],  // log_bc_ac_weight
      (const float*)d_in[5],  // log_ac_tau_rise
      (const float*)d_in[6],  // log_ac_tau_decay
      (const float*)d_in[7],  // log_ac_sigmoid_slope
      (const float*)d_in[8],  // ac_sigmoid_offset
      (const float*)d_in[9],  // log_ac_bc_weight
      (const float*)d_in[10], // out_scale
      (float*)d_out);
}